// Round 1
// baseline (1464.866 us; speedup 1.0000x reference)
//
#include <hip/hip_runtime.h>
#include <hip/hip_bf16.h>

// MaskedMoE: T=2048 tokens, d=1024, d_ff=4096, E=8 experts, top-2 routing.
// Pipeline: router -> prefix -> gather-GEMM1+gelu -> GEMM2*w -> combine(2 rows).
// Top-2 sparse == reference exactly (combine==0 terms contribute exact 0).

#define T_TOK 2048
#define D_EMB 1024
#define DFF   4096
#define NE    8

__device__ __forceinline__ float gelu_tanh(float x) {
    // jax.nn.gelu(approximate=True): 0.5*x*(1+tanh(sqrt(2/pi)*(x+0.044715*x^3)))
    const float c = 0.7978845608028654f;
    float x3 = x * x * x;
    return 0.5f * x * (1.0f + tanhf(c * (x + 0.044715f * x3)));
}

__global__ void k_zero(int* counts) {
    if (threadIdx.x < NE) counts[threadIdx.x] = 0;
}

// One wave (64 lanes) per token: 8 router dots, softmax, top-2, compaction.
__global__ __launch_bounds__(256) void k_router(
    const float* __restrict__ x, const float* __restrict__ mask,
    const float* __restrict__ Wr,
    int* __restrict__ counts, int* __restrict__ elist, float* __restrict__ wlist,
    int* __restrict__ tok_e, int* __restrict__ tok_p) {
    int wave = threadIdx.x >> 6;
    int lane = threadIdx.x & 63;
    int t = blockIdx.x * 4 + wave;
    if (t >= T_TOK) return;

    float acc[NE];
#pragma unroll
    for (int e = 0; e < NE; e++) acc[e] = 0.f;
    const float* xr = x + (size_t)t * D_EMB;
    for (int c = 0; c < D_EMB / 64; c++) {
        int i = c * 64 + lane;
        float xv = xr[i];
        const float* wr = Wr + (size_t)i * NE;
#pragma unroll
        for (int e = 0; e < NE; e++) acc[e] += xv * wr[e];
    }
#pragma unroll
    for (int e = 0; e < NE; e++) {
#pragma unroll
        for (int off = 32; off > 0; off >>= 1)
            acc[e] += __shfl_xor(acc[e], off);
    }
    if (lane == 0) {
        float p[NE];
        float mx = -1e30f;
#pragma unroll
        for (int e = 0; e < NE; e++) {
            p[e] = acc[e] * mask[t * NE + e];
            mx = fmaxf(mx, p[e]);
        }
        float s = 0.f;
#pragma unroll
        for (int e = 0; e < NE; e++) { p[e] = expf(p[e] - mx); s += p[e]; }
#pragma unroll
        for (int e = 0; e < NE; e++) p[e] /= s;
        // top-2, ties -> lowest index (jax.lax.top_k semantics)
        int e0 = 0; float b0 = p[0];
#pragma unroll
        for (int e = 1; e < NE; e++) if (p[e] > b0) { b0 = p[e]; e0 = e; }
        int e1 = -1; float b1 = -1.f;
#pragma unroll
        for (int e = 0; e < NE; e++) if (e != e0 && p[e] > b1) { b1 = p[e]; e1 = e; }

        int pos0 = atomicAdd(&counts[e0], 1);
        elist[e0 * T_TOK + pos0] = t;
        wlist[e0 * T_TOK + pos0] = b0;
        tok_e[t * 2 + 0] = e0; tok_p[t * 2 + 0] = pos0;

        int pos1 = atomicAdd(&counts[e1], 1);
        elist[e1 * T_TOK + pos1] = t;
        wlist[e1 * T_TOK + pos1] = b1;
        tok_e[t * 2 + 1] = e1; tok_p[t * 2 + 1] = pos1;
    }
}

__global__ void k_prefix(const int* __restrict__ counts, int* __restrict__ base) {
    if (threadIdx.x == 0) {
        int s = 0;
        for (int e = 0; e < NE; e++) { base[e] = s; s += counts[e]; }
        base[NE] = s;
    }
}

// GEMM1: H[base[e]+p, :] = gelu(x[elist[e,p], :] @ W1[e])   [cnt_e x 1024] @ [1024 x 4096]
// 64x64 tile, BK=16, 256 threads, 4x4 per thread.
__global__ __launch_bounds__(256) void k_gemm1(
    const float* __restrict__ x, const float* __restrict__ W1,
    const int* __restrict__ counts, const int* __restrict__ base,
    const int* __restrict__ elist, float* __restrict__ H) {
    int e = blockIdx.z;
    int cnt = counts[e];
    int p0 = blockIdx.y * 64;
    if (p0 >= cnt) return;
    int n0 = blockIdx.x * 64;
    const float* B = W1 + (size_t)e * D_EMB * DFF;

    __shared__ float As[16][64];
    __shared__ float Bs[16][64];
    __shared__ int ttok[64];

    int tid = threadIdx.x;
    if (tid < 64) {
        int p = p0 + tid;
        ttok[tid] = elist[e * T_TOK + min(p, cnt - 1)];
    }
    __syncthreads();

    int arow = tid >> 2, ac4 = tid & 3;     // A: 64 rows x 4 float4
    int brow = tid >> 4, bc4 = tid & 15;    // B: 16 rows x 16 float4
    int tm = tid >> 4, tn = tid & 15;       // 16x16 threads, 4x4 each

    const float* aptr = x + (size_t)ttok[arow] * D_EMB + ac4 * 4;

    float acc[4][4] = {};
    for (int k0 = 0; k0 < D_EMB; k0 += 16) {
        float4 av = *(const float4*)(aptr + k0);
        float4 bv = *(const float4*)(B + (size_t)(k0 + brow) * DFF + n0 + bc4 * 4);
        __syncthreads();
        As[ac4 * 4 + 0][arow] = av.x;
        As[ac4 * 4 + 1][arow] = av.y;
        As[ac4 * 4 + 2][arow] = av.z;
        As[ac4 * 4 + 3][arow] = av.w;
        *(float4*)(&Bs[brow][bc4 * 4]) = bv;
        __syncthreads();
#pragma unroll
        for (int k = 0; k < 16; k++) {
            float4 a4 = *(const float4*)(&As[k][tm * 4]);
            float4 b4 = *(const float4*)(&Bs[k][tn * 4]);
            float aa[4] = {a4.x, a4.y, a4.z, a4.w};
            float bb[4] = {b4.x, b4.y, b4.z, b4.w};
#pragma unroll
            for (int i = 0; i < 4; i++)
#pragma unroll
                for (int j = 0; j < 4; j++) acc[i][j] += aa[i] * bb[j];
        }
    }

    int rowbase = base[e];
#pragma unroll
    for (int i = 0; i < 4; i++) {
        int p = p0 + tm * 4 + i;
        if (p < cnt) {
            float4 o;
            o.x = gelu_tanh(acc[i][0]);
            o.y = gelu_tanh(acc[i][1]);
            o.z = gelu_tanh(acc[i][2]);
            o.w = gelu_tanh(acc[i][3]);
            *(float4*)(H + (size_t)(rowbase + p) * DFF + n0 + tn * 4) = o;
        }
    }
}

// GEMM2: O[row, :] = w[row] * (H[row, :] @ W2[e])   [cnt_e x 4096] @ [4096 x 1024]
__global__ __launch_bounds__(256) void k_gemm2(
    const float* __restrict__ H, const float* __restrict__ W2,
    const int* __restrict__ counts, const int* __restrict__ base,
    const float* __restrict__ wlist, float* __restrict__ O) {
    int e = blockIdx.z;
    int cnt = counts[e];
    int p0 = blockIdx.y * 64;
    if (p0 >= cnt) return;
    int n0 = blockIdx.x * 64;
    const float* B = W2 + (size_t)e * DFF * D_EMB;
    int rowbase = base[e];

    __shared__ float As[16][64];
    __shared__ float Bs[16][64];

    int tid = threadIdx.x;
    int arow = tid >> 2, ac4 = tid & 3;
    int brow = tid >> 4, bc4 = tid & 15;
    int tm = tid >> 4, tn = tid & 15;

    int prow = min(p0 + arow, cnt - 1);
    const float* aptr = H + (size_t)(rowbase + prow) * DFF + ac4 * 4;

    float acc[4][4] = {};
    for (int k0 = 0; k0 < DFF; k0 += 16) {
        float4 av = *(const float4*)(aptr + k0);
        float4 bv = *(const float4*)(B + (size_t)(k0 + brow) * D_EMB + n0 + bc4 * 4);
        __syncthreads();
        As[ac4 * 4 + 0][arow] = av.x;
        As[ac4 * 4 + 1][arow] = av.y;
        As[ac4 * 4 + 2][arow] = av.z;
        As[ac4 * 4 + 3][arow] = av.w;
        *(float4*)(&Bs[brow][bc4 * 4]) = bv;
        __syncthreads();
#pragma unroll
        for (int k = 0; k < 16; k++) {
            float4 a4 = *(const float4*)(&As[k][tm * 4]);
            float4 b4 = *(const float4*)(&Bs[k][tn * 4]);
            float aa[4] = {a4.x, a4.y, a4.z, a4.w};
            float bb[4] = {b4.x, b4.y, b4.z, b4.w};
#pragma unroll
            for (int i = 0; i < 4; i++)
#pragma unroll
                for (int j = 0; j < 4; j++) acc[i][j] += aa[i] * bb[j];
        }
    }

#pragma unroll
    for (int i = 0; i < 4; i++) {
        int p = p0 + tm * 4 + i;
        if (p < cnt) {
            float w = wlist[e * T_TOK + p];
            float4 o;
            o.x = acc[i][0] * w;
            o.y = acc[i][1] * w;
            o.z = acc[i][2] * w;
            o.w = acc[i][3] * w;
            *(float4*)(O + (size_t)(rowbase + p) * D_EMB + n0 + tn * 4) = o;
        }
    }
}

// out[t,:] = O[row(t,0),:] + O[row(t,1),:]  (K=2 add is commutative -> exact)
__global__ __launch_bounds__(256) void k_final(
    const float* __restrict__ O, const int* __restrict__ base,
    const int* __restrict__ tok_e, const int* __restrict__ tok_p,
    float* __restrict__ out) {
    int t = blockIdx.x;
    int r0 = base[tok_e[t * 2 + 0]] + tok_p[t * 2 + 0];
    int r1 = base[tok_e[t * 2 + 1]] + tok_p[t * 2 + 1];
    int i = threadIdx.x * 4;
    float4 a = *(const float4*)(O + (size_t)r0 * D_EMB + i);
    float4 b = *(const float4*)(O + (size_t)r1 * D_EMB + i);
    float4 o;
    o.x = a.x + b.x; o.y = a.y + b.y; o.z = a.z + b.z; o.w = a.w + b.w;
    *(float4*)(out + (size_t)t * D_EMB + i) = o;
}

extern "C" void kernel_launch(void* const* d_in, const int* in_sizes, int n_in,
                              void* d_out, int out_size, void* d_ws, size_t ws_size,
                              hipStream_t stream) {
    const float* x    = (const float*)d_in[0];   // [1,2048,1024]
    const float* mask = (const float*)d_in[1];   // [2048,8]
    const float* Wr   = (const float*)d_in[2];   // [1024,8]
    const float* W1   = (const float*)d_in[3];   // [8,1024,4096]
    const float* W2   = (const float*)d_in[4];   // [8,4096,1024]
    float* out = (float*)d_out;                  // [2048,1024]

    // workspace layout (needs ~80.2 MB)
    char* ws = (char*)d_ws;
    int*   counts = (int*)(ws + 0);            // 8 ints
    int*   base   = (int*)(ws + 64);           // 9 ints
    int*   tok_e  = (int*)(ws + 128);          // 2*2048
    int*   tok_p  = (int*)(ws + 128 + 16384);  // 2*2048
    int*   elist  = (int*)(ws + 128 + 32768);  // 8*2048
    float* wlist  = (float*)(ws + 128 + 32768 + 65536);
    size_t off = 128 + 32768 + 2 * 65536;
    off = (off + 255) & ~(size_t)255;
    float* H = (float*)(ws + off);             // [4096,4096] fp32 = 64 MB
    off += (size_t)4096 * DFF * 4;
    float* O = (float*)(ws + off);             // [4096,1024] fp32 = 16 MB

    k_zero<<<1, 64, 0, stream>>>(counts);
    k_router<<<T_TOK / 4, 256, 0, stream>>>(x, mask, Wr, counts, elist, wlist, tok_e, tok_p);
    k_prefix<<<1, 64, 0, stream>>>(counts, base);
    k_gemm1<<<dim3(DFF / 64, T_TOK / 64, NE), 256, 0, stream>>>(x, W1, counts, base, elist, H);
    k_gemm2<<<dim3(D_EMB / 64, T_TOK / 64, NE), 256, 0, stream>>>(H, W2, counts, base, wlist, O);
    k_final<<<T_TOK, 256, 0, stream>>>(O, base, tok_e, tok_p, out);
}

// Round 2
// 568.174 us; speedup vs baseline: 2.5782x; 2.5782x over previous
//
#include <hip/hip_runtime.h>
#include <hip/hip_bf16.h>

// MaskedMoE: T=2048, d=1024, d_ff=4096, E=8, top-2.
// R1: f16-MFMA GEMMs (m97 structure: 128x128 tile, BK=32, global_load_lds w=16).
// W1/W2 pre-transposed to [N][K] fp16 in a 32MB buffer reused 4x (two N-halves of
// W1, two K-halves of W2 w/ split-K atomic epilogue) to stay under proven ws>=80MB.

#define T_TOK 2048
#define D_EMB 1024
#define DFF   4096
#define NE    8

typedef _Float16 f16x8 __attribute__((ext_vector_type(8)));
typedef _Float16 f16x4 __attribute__((ext_vector_type(4)));
typedef float    f32x4 __attribute__((ext_vector_type(4)));

__device__ __forceinline__ float gelu_tanh(float x) {
    const float c = 0.7978845608028654f;
    float x3 = x * x * x;
    return 0.5f * x * (1.0f + tanhf(c * (x + 0.044715f * x3)));
}

// async global->LDS, 16B per lane. LDS dest must be wave-uniform base (+lane*16 by HW).
__device__ __forceinline__ void gll(const void* g, void* l) {
    __builtin_amdgcn_global_load_lds((__attribute__((address_space(1))) void*)g,
                                     (__attribute__((address_space(3))) void*)l,
                                     16, 0, 0);
}

__global__ void k_zero(int* counts) {
    if (threadIdx.x < NE) counts[threadIdx.x] = 0;
}

__global__ __launch_bounds__(256) void k_cvt_x(const float4* __restrict__ x4,
                                               _Float16* __restrict__ xh) {
    int i = blockIdx.x * 256 + threadIdx.x;
    float4 v = x4[i];
    f16x4 o;
    o[0] = (_Float16)v.x; o[1] = (_Float16)v.y;
    o[2] = (_Float16)v.z; o[3] = (_Float16)v.w;
    *(f16x4*)(xh + (size_t)i * 4) = o;
}

// fp32 [K][N] (src_ld=N) tile -> fp16 [N][K] (dst_ld), 64x64 tiles, per expert.
// Expert strides: src 4M elems, dst 2M elems (same for W1 and W2 cases).
__global__ __launch_bounds__(256) void k_transpose(
    const float* __restrict__ src, _Float16* __restrict__ dst,
    int src_ld, int dst_ld, int src_k0, int src_n0) {
    __shared__ float tile[64][65];
    int e = blockIdx.z;
    const float* S = src + (size_t)e * 4194304;
    _Float16* D = dst + (size_t)e * 2097152;
    int t = threadIdx.x;
    int kb = src_k0 + blockIdx.y * 64;
    int nb = src_n0 + blockIdx.x * 64;
#pragma unroll
    for (int i = 0; i < 4; i++) {
        int r = (t >> 4) + i * 16;
        int c = (t & 15) * 4;
        float4 v = *(const float4*)(S + (size_t)(kb + r) * src_ld + nb + c);
        tile[r][c + 0] = v.x; tile[r][c + 1] = v.y;
        tile[r][c + 2] = v.z; tile[r][c + 3] = v.w;
    }
    __syncthreads();
    int drb = blockIdx.x * 64, dcb = blockIdx.y * 64;
#pragma unroll
    for (int j = 0; j < 2; j++) {
        int idx = j * 256 + t;
        int n = idx >> 3, kc = idx & 7;
        f16x8 o;
#pragma unroll
        for (int u = 0; u < 8; u++) o[u] = (_Float16)tile[kc * 8 + u][n];
        *(f16x8*)(D + (size_t)(drb + n) * dst_ld + dcb + kc * 8) = o;
    }
}

// One wave per token: router logits, softmax, top-2, per-expert compaction.
__global__ __launch_bounds__(256) void k_router(
    const float* __restrict__ x, const float* __restrict__ mask,
    const float* __restrict__ Wr,
    int* __restrict__ counts, int* __restrict__ elist, float* __restrict__ wlist) {
    int wave = threadIdx.x >> 6;
    int lane = threadIdx.x & 63;
    int t = blockIdx.x * 4 + wave;
    if (t >= T_TOK) return;

    float acc[NE];
#pragma unroll
    for (int e = 0; e < NE; e++) acc[e] = 0.f;
    const float* xr = x + (size_t)t * D_EMB;
    for (int c = 0; c < D_EMB / 64; c++) {
        int i = c * 64 + lane;
        float xv = xr[i];
        const float* wr = Wr + (size_t)i * NE;
#pragma unroll
        for (int e = 0; e < NE; e++) acc[e] += xv * wr[e];
    }
#pragma unroll
    for (int e = 0; e < NE; e++) {
#pragma unroll
        for (int off = 32; off > 0; off >>= 1)
            acc[e] += __shfl_xor(acc[e], off);
    }
    if (lane == 0) {
        float p[NE];
        float mx = -1e30f;
#pragma unroll
        for (int e = 0; e < NE; e++) {
            p[e] = acc[e] * mask[t * NE + e];
            mx = fmaxf(mx, p[e]);
        }
        float s = 0.f;
#pragma unroll
        for (int e = 0; e < NE; e++) { p[e] = expf(p[e] - mx); s += p[e]; }
#pragma unroll
        for (int e = 0; e < NE; e++) p[e] /= s;
        int e0 = 0; float b0 = p[0];
#pragma unroll
        for (int e = 1; e < NE; e++) if (p[e] > b0) { b0 = p[e]; e0 = e; }
        int e1 = -1; float b1 = -1.f;
#pragma unroll
        for (int e = 0; e < NE; e++) if (e != e0 && p[e] > b1) { b1 = p[e]; e1 = e; }

        int pos0 = atomicAdd(&counts[e0], 1);
        elist[e0 * T_TOK + pos0] = t;
        wlist[e0 * T_TOK + pos0] = b0;
        int pos1 = atomicAdd(&counts[e1], 1);
        elist[e1 * T_TOK + pos1] = t;
        wlist[e1 * T_TOK + pos1] = b1;
    }
}

__global__ void k_prefix(const int* __restrict__ counts, int* __restrict__ base) {
    if (threadIdx.x == 0) {
        int s = 0;
        for (int e = 0; e < NE; e++) { base[e] = s; s += counts[e]; }
        base[NE] = s;
    }
}

// GEMM1: H[base[e]+p, n0g+0..2047] = gelu(x[tok] @ W1T_half^T), f16 MFMA.
// Tile 128x128, BK=32, 4 waves (2x2 of 64x64), 16 mfma_f32_16x16x32_f16 / K-step.
__global__ __launch_bounds__(256) void k_gemm1(
    const _Float16* __restrict__ xh, const _Float16* __restrict__ BT,
    const int* __restrict__ counts, const int* __restrict__ base,
    const int* __restrict__ elist, _Float16* __restrict__ H, int n0g) {
    int e = blockIdx.z;
    int cnt = counts[e];
    int p0 = blockIdx.y * 128;
    if (p0 >= cnt) return;
    int n0 = blockIdx.x * 128;   // within [0,2048) half buffer
    const _Float16* B = BT + (size_t)e * 2097152;

    __shared__ _Float16 As[128 * 32];
    __shared__ _Float16 Bs[128 * 32];
    __shared__ int ttok[128];

    int tid = threadIdx.x;
    if (tid < 128) ttok[tid] = elist[e * T_TOK + min(p0 + tid, cnt - 1)];
    __syncthreads();

    int w = tid >> 6, lane = tid & 63;
    int c0 = tid, c1 = tid + 256;
    const _Float16* pA0 = xh + (size_t)ttok[c0 >> 2] * D_EMB + (c0 & 3) * 8;
    const _Float16* pA1 = xh + (size_t)ttok[c1 >> 2] * D_EMB + (c1 & 3) * 8;
    const _Float16* pB0 = B + (size_t)(n0 + (c0 >> 2)) * 1024 + (c0 & 3) * 8;
    const _Float16* pB1 = B + (size_t)(n0 + (c1 >> 2)) * 1024 + (c1 & 3) * 8;
    _Float16* ldsA0 = As + (w * 64) * 8;
    _Float16* ldsA1 = As + (256 + w * 64) * 8;
    _Float16* ldsB0 = Bs + (w * 64) * 8;
    _Float16* ldsB1 = Bs + (256 + w * 64) * 8;

    int wm = w >> 1, wn = w & 1;
    int lhi = lane >> 4, llo = lane & 15;
    const _Float16* arp = As + ((wm * 64 + llo) * 32 + lhi * 8);
    const _Float16* brp = Bs + ((wn * 64 + llo) * 32 + lhi * 8);

    f32x4 acc[4][4] = {};
    for (int k0 = 0; k0 < D_EMB; k0 += 32) {
        __syncthreads();
        gll(pA0, ldsA0); gll(pA1, ldsA1);
        gll(pB0, ldsB0); gll(pB1, ldsB1);
        pA0 += 32; pA1 += 32; pB0 += 32; pB1 += 32;
        __syncthreads();
        f16x8 a[4], b[4];
#pragma unroll
        for (int i = 0; i < 4; i++) {
            a[i] = *(const f16x8*)(arp + i * 512);
            b[i] = *(const f16x8*)(brp + i * 512);
        }
#pragma unroll
        for (int mt = 0; mt < 4; mt++)
#pragma unroll
            for (int nt = 0; nt < 4; nt++)
                acc[mt][nt] = __builtin_amdgcn_mfma_f32_16x16x32_f16(a[mt], b[nt], acc[mt][nt], 0, 0, 0);
    }

    int rowbase = base[e];
#pragma unroll
    for (int mt = 0; mt < 4; mt++) {
#pragma unroll
        for (int i = 0; i < 4; i++) {
            int p = p0 + wm * 64 + mt * 16 + lhi * 4 + i;
            if (p < cnt) {
                size_t rowoff = (size_t)(rowbase + p) * DFF + n0g + n0 + wn * 64 + llo;
#pragma unroll
                for (int nt = 0; nt < 4; nt++)
                    H[rowoff + nt * 16] = (_Float16)gelu_tanh(acc[mt][nt][i]);
            }
        }
    }
}

// GEMM2 (split-K half): out[tok, :] += w * (H[row, kh..kh+2047] @ W2T_half^T), atomic.
__global__ __launch_bounds__(256) void k_gemm2(
    const _Float16* __restrict__ H, const _Float16* __restrict__ BT,
    const int* __restrict__ counts, const int* __restrict__ base,
    const int* __restrict__ elist, const float* __restrict__ wlist,
    float* __restrict__ out, int kh) {
    int e = blockIdx.z;
    int cnt = counts[e];
    int p0 = blockIdx.y * 128;
    if (p0 >= cnt) return;
    int n0 = blockIdx.x * 128;
    const _Float16* B = BT + (size_t)e * 2097152;
    int rowbase = base[e];

    __shared__ _Float16 As[128 * 32];
    __shared__ _Float16 Bs[128 * 32];
    __shared__ int ttok[128];
    __shared__ float twt[128];

    int tid = threadIdx.x;
    if (tid < 128) {
        int p = min(p0 + tid, cnt - 1);
        ttok[tid] = elist[e * T_TOK + p];
        twt[tid]  = wlist[e * T_TOK + p];
    }

    int w = tid >> 6, lane = tid & 63;
    int c0 = tid, c1 = tid + 256;
    int r0 = rowbase + min(p0 + (c0 >> 2), cnt - 1);
    int r1 = rowbase + min(p0 + (c1 >> 2), cnt - 1);
    const _Float16* pA0 = H + (size_t)r0 * DFF + kh + (c0 & 3) * 8;
    const _Float16* pA1 = H + (size_t)r1 * DFF + kh + (c1 & 3) * 8;
    const _Float16* pB0 = B + (size_t)(n0 + (c0 >> 2)) * 2048 + (c0 & 3) * 8;
    const _Float16* pB1 = B + (size_t)(n0 + (c1 >> 2)) * 2048 + (c1 & 3) * 8;
    _Float16* ldsA0 = As + (w * 64) * 8;
    _Float16* ldsA1 = As + (256 + w * 64) * 8;
    _Float16* ldsB0 = Bs + (w * 64) * 8;
    _Float16* ldsB1 = Bs + (256 + w * 64) * 8;

    int wm = w >> 1, wn = w & 1;
    int lhi = lane >> 4, llo = lane & 15;
    const _Float16* arp = As + ((wm * 64 + llo) * 32 + lhi * 8);
    const _Float16* brp = Bs + ((wn * 64 + llo) * 32 + lhi * 8);

    f32x4 acc[4][4] = {};
    for (int k0 = 0; k0 < 2048; k0 += 32) {
        __syncthreads();
        gll(pA0, ldsA0); gll(pA1, ldsA1);
        gll(pB0, ldsB0); gll(pB1, ldsB1);
        pA0 += 32; pA1 += 32; pB0 += 32; pB1 += 32;
        __syncthreads();
        f16x8 a[4], b[4];
#pragma unroll
        for (int i = 0; i < 4; i++) {
            a[i] = *(const f16x8*)(arp + i * 512);
            b[i] = *(const f16x8*)(brp + i * 512);
        }
#pragma unroll
        for (int mt = 0; mt < 4; mt++)
#pragma unroll
            for (int nt = 0; nt < 4; nt++)
                acc[mt][nt] = __builtin_amdgcn_mfma_f32_16x16x32_f16(a[mt], b[nt], acc[mt][nt], 0, 0, 0);
    }

#pragma unroll
    for (int mt = 0; mt < 4; mt++) {
#pragma unroll
        for (int i = 0; i < 4; i++) {
            int pl = wm * 64 + mt * 16 + lhi * 4 + i;
            int p = p0 + pl;
            if (p < cnt) {
                int t = ttok[pl];
                float wgt = twt[pl];
                size_t o = (size_t)t * D_EMB + n0 + wn * 64 + llo;
#pragma unroll
                for (int nt = 0; nt < 4; nt++)
                    atomicAdd(&out[o + nt * 16], acc[mt][nt][i] * wgt);
            }
        }
    }
}

extern "C" void kernel_launch(void* const* d_in, const int* in_sizes, int n_in,
                              void* d_out, int out_size, void* d_ws, size_t ws_size,
                              hipStream_t stream) {
    const float* x    = (const float*)d_in[0];
    const float* mask = (const float*)d_in[1];
    const float* Wr   = (const float*)d_in[2];
    const float* W1   = (const float*)d_in[3];   // [8,1024,4096]
    const float* W2   = (const float*)d_in[4];   // [8,4096,1024]
    float* out = (float*)d_out;

    // ws layout (peak 68.3 MB; proven ws_size >= 80.2 MB)
    char* ws = (char*)d_ws;
    int*      counts = (int*)(ws + 0);
    int*      base   = (int*)(ws + 256);
    int*      elist  = (int*)(ws + 512);                 // 8*2048 ints
    float*    wlist  = (float*)(ws + 512 + 65536);       // 8*2048 floats
    _Float16* xh     = (_Float16*)(ws + 262144);         // 2048x1024   (4 MB)
    _Float16* H      = (_Float16*)(ws + 262144 + 4194304);          // 4096x4096 (32 MB)
    _Float16* Wbuf   = (_Float16*)(ws + 262144 + 4194304 + 33554432); // 32 MB, reused 4x

    hipMemsetAsync(d_out, 0, (size_t)T_TOK * D_EMB * 4, stream);
    k_zero<<<1, 64, 0, stream>>>(counts);
    k_cvt_x<<<T_TOK * D_EMB / 4 / 256, 256, 0, stream>>>((const float4*)x, xh);
    k_router<<<T_TOK / 4, 256, 0, stream>>>(x, mask, Wr, counts, elist, wlist);
    k_prefix<<<1, 64, 0, stream>>>(counts, base);

    // GEMM1 in two N-halves of W1 (transposed to [2048][1024] fp16 per expert)
    for (int h = 0; h < 2; h++) {
        k_transpose<<<dim3(32, 16, NE), 256, 0, stream>>>(W1, Wbuf, DFF, 1024, 0, h * 2048);
        k_gemm1<<<dim3(16, 16, NE), 256, 0, stream>>>(xh, Wbuf, counts, base, elist, H, h * 2048);
    }
    // GEMM2 in two K-halves of W2 (transposed to [1024][2048] fp16 per expert), atomic +=
    for (int h = 0; h < 2; h++) {
        k_transpose<<<dim3(16, 32, NE), 256, 0, stream>>>(W2, Wbuf, D_EMB, 2048, h * 2048, 0);
        k_gemm2<<<dim3(8, 16, NE), 256, 0, stream>>>(H, Wbuf, counts, base, elist, wlist, out, h * 2048);
    }
}

// Round 3
// 543.289 us; speedup vs baseline: 2.6963x; 1.0458x over previous
//
#include <hip/hip_runtime.h>
#include <hip/hip_bf16.h>

// MaskedMoE: T=2048, d=1024, d_ff=4096, E=8, top-2.
// R2: ws_size proven = 512MiB -> full W1T+W2T fp16 (no buffer reuse serialization),
// GEMM2 split-K=2 into two O buffers (no atomics, no memset), weights applied in
// k_final. GEMMs: m97 structure (128x128 tile, BK=32, global_load_lds w=16, f16 MFMA).

#define T_TOK 2048
#define D_EMB 1024
#define DFF   4096
#define NE    8

typedef _Float16 f16x8 __attribute__((ext_vector_type(8)));
typedef _Float16 f16x4 __attribute__((ext_vector_type(4)));
typedef float    f32x4 __attribute__((ext_vector_type(4)));

__device__ __forceinline__ float gelu_tanh(float x) {
    const float c = 0.7978845608028654f;
    float z = c * (x + 0.044715f * x * x * x);
    // tanh(z) = 1 - 2/(exp(2z)+1), fast-exp path
    float u = __expf(2.0f * z);
    float th = (u - 1.0f) / (u + 1.0f);
    return 0.5f * x * (1.0f + th);
}

__device__ __forceinline__ void gll(const void* g, void* l) {
    __builtin_amdgcn_global_load_lds((__attribute__((address_space(1))) void*)g,
                                     (__attribute__((address_space(3))) void*)l,
                                     16, 0, 0);
}

__global__ void k_zero(int* counts) {
    if (threadIdx.x < NE) counts[threadIdx.x] = 0;
}

__global__ __launch_bounds__(256) void k_cvt_x(const float4* __restrict__ x4,
                                               _Float16* __restrict__ xh) {
    int i = blockIdx.x * 256 + threadIdx.x;
    float4 v = x4[i];
    f16x4 o;
    o[0] = (_Float16)v.x; o[1] = (_Float16)v.y;
    o[2] = (_Float16)v.z; o[3] = (_Float16)v.w;
    *(f16x4*)(xh + (size_t)i * 4) = o;
}

// fp32 [K][N] (ld=src_ld) -> fp16 [N][K] (ld=dst_ld), 64x64 tiles, expert stride 4M elems.
__global__ __launch_bounds__(256) void k_transpose(
    const float* __restrict__ src, _Float16* __restrict__ dst,
    int src_ld, int dst_ld) {
    __shared__ float tile[64][65];
    int e = blockIdx.z;
    const float* S = src + (size_t)e * 4194304;
    _Float16* D = dst + (size_t)e * 4194304;
    int t = threadIdx.x;
    int kb = blockIdx.y * 64;
    int nb = blockIdx.x * 64;
#pragma unroll
    for (int i = 0; i < 4; i++) {
        int r = (t >> 4) + i * 16;
        int c = (t & 15) * 4;
        float4 v = *(const float4*)(S + (size_t)(kb + r) * src_ld + nb + c);
        tile[r][c + 0] = v.x; tile[r][c + 1] = v.y;
        tile[r][c + 2] = v.z; tile[r][c + 3] = v.w;
    }
    __syncthreads();
#pragma unroll
    for (int j = 0; j < 2; j++) {
        int idx = j * 256 + t;
        int n = idx >> 3, kc = idx & 7;
        f16x8 o;
#pragma unroll
        for (int u = 0; u < 8; u++) o[u] = (_Float16)tile[kc * 8 + u][n];
        *(f16x8*)(D + (size_t)(nb + n) * dst_ld + kb + kc * 8) = o;
    }
}

// One wave per token: router logits, softmax, top-2, per-expert compaction.
__global__ __launch_bounds__(256) void k_router(
    const float* __restrict__ x, const float* __restrict__ mask,
    const float* __restrict__ Wr,
    int* __restrict__ counts, int* __restrict__ elist,
    int* __restrict__ tok_e, int* __restrict__ tok_p, float* __restrict__ tok_w) {
    int wave = threadIdx.x >> 6;
    int lane = threadIdx.x & 63;
    int t = blockIdx.x * 4 + wave;
    if (t >= T_TOK) return;

    float acc[NE];
#pragma unroll
    for (int e = 0; e < NE; e++) acc[e] = 0.f;
    const float* xr = x + (size_t)t * D_EMB;
    for (int c = 0; c < D_EMB / 64; c++) {
        int i = c * 64 + lane;
        float xv = xr[i];
        const float* wr = Wr + (size_t)i * NE;
#pragma unroll
        for (int e = 0; e < NE; e++) acc[e] += xv * wr[e];
    }
#pragma unroll
    for (int e = 0; e < NE; e++) {
#pragma unroll
        for (int off = 32; off > 0; off >>= 1)
            acc[e] += __shfl_xor(acc[e], off);
    }
    if (lane == 0) {
        float p[NE];
        float mx = -1e30f;
#pragma unroll
        for (int e = 0; e < NE; e++) {
            p[e] = acc[e] * mask[t * NE + e];
            mx = fmaxf(mx, p[e]);
        }
        float s = 0.f;
#pragma unroll
        for (int e = 0; e < NE; e++) { p[e] = expf(p[e] - mx); s += p[e]; }
#pragma unroll
        for (int e = 0; e < NE; e++) p[e] /= s;
        int e0 = 0; float b0 = p[0];
#pragma unroll
        for (int e = 1; e < NE; e++) if (p[e] > b0) { b0 = p[e]; e0 = e; }
        int e1 = -1; float b1 = -1.f;
#pragma unroll
        for (int e = 0; e < NE; e++) if (e != e0 && p[e] > b1) { b1 = p[e]; e1 = e; }

        int pos0 = atomicAdd(&counts[e0], 1);
        elist[e0 * T_TOK + pos0] = t;
        tok_e[t * 2 + 0] = e0; tok_p[t * 2 + 0] = pos0; tok_w[t * 2 + 0] = b0;
        int pos1 = atomicAdd(&counts[e1], 1);
        elist[e1 * T_TOK + pos1] = t;
        tok_e[t * 2 + 1] = e1; tok_p[t * 2 + 1] = pos1; tok_w[t * 2 + 1] = b1;
    }
}

__global__ void k_prefix(const int* __restrict__ counts, int* __restrict__ base) {
    if (threadIdx.x == 0) {
        int s = 0;
        for (int e = 0; e < NE; e++) { base[e] = s; s += counts[e]; }
        base[NE] = s;
    }
}

// GEMM1: H[base[e]+p, :] = gelu(x[elist[e,p], :] @ W1[e]), full N=4096, K=1024.
__global__ __launch_bounds__(256) void k_gemm1(
    const _Float16* __restrict__ xh, const _Float16* __restrict__ BT,
    const int* __restrict__ counts, const int* __restrict__ base,
    const int* __restrict__ elist, _Float16* __restrict__ H) {
    int e = blockIdx.z;
    int cnt = counts[e];
    int p0 = blockIdx.y * 128;
    if (p0 >= cnt) return;
    int n0 = blockIdx.x * 128;
    const _Float16* B = BT + (size_t)e * 4194304;   // [4096 n][1024 k]

    __shared__ _Float16 As[128 * 32];
    __shared__ _Float16 Bs[128 * 32];
    __shared__ int ttok[128];

    int tid = threadIdx.x;
    if (tid < 128) ttok[tid] = elist[e * T_TOK + min(p0 + tid, cnt - 1)];
    __syncthreads();

    int w = tid >> 6, lane = tid & 63;
    int c0 = tid, c1 = tid + 256;
    const _Float16* pA0 = xh + (size_t)ttok[c0 >> 2] * D_EMB + (c0 & 3) * 8;
    const _Float16* pA1 = xh + (size_t)ttok[c1 >> 2] * D_EMB + (c1 & 3) * 8;
    const _Float16* pB0 = B + (size_t)(n0 + (c0 >> 2)) * 1024 + (c0 & 3) * 8;
    const _Float16* pB1 = B + (size_t)(n0 + (c1 >> 2)) * 1024 + (c1 & 3) * 8;
    _Float16* ldsA0 = As + (w * 64) * 8;
    _Float16* ldsA1 = As + (256 + w * 64) * 8;
    _Float16* ldsB0 = Bs + (w * 64) * 8;
    _Float16* ldsB1 = Bs + (256 + w * 64) * 8;

    int wm = w >> 1, wn = w & 1;
    int lhi = lane >> 4, llo = lane & 15;
    const _Float16* arp = As + ((wm * 64 + llo) * 32 + lhi * 8);
    const _Float16* brp = Bs + ((wn * 64 + llo) * 32 + lhi * 8);

    f32x4 acc[4][4] = {};
    for (int k0 = 0; k0 < D_EMB; k0 += 32) {
        __syncthreads();
        gll(pA0, ldsA0); gll(pA1, ldsA1);
        gll(pB0, ldsB0); gll(pB1, ldsB1);
        pA0 += 32; pA1 += 32; pB0 += 32; pB1 += 32;
        __syncthreads();
        f16x8 a[4], b[4];
#pragma unroll
        for (int i = 0; i < 4; i++) {
            a[i] = *(const f16x8*)(arp + i * 512);
            b[i] = *(const f16x8*)(brp + i * 512);
        }
#pragma unroll
        for (int mt = 0; mt < 4; mt++)
#pragma unroll
            for (int nt = 0; nt < 4; nt++)
                acc[mt][nt] = __builtin_amdgcn_mfma_f32_16x16x32_f16(a[mt], b[nt], acc[mt][nt], 0, 0, 0);
    }

    int rowbase = base[e];
#pragma unroll
    for (int mt = 0; mt < 4; mt++) {
#pragma unroll
        for (int i = 0; i < 4; i++) {
            int p = p0 + wm * 64 + mt * 16 + lhi * 4 + i;
            if (p < cnt) {
                size_t rowoff = (size_t)(rowbase + p) * DFF + n0 + wn * 64 + llo;
#pragma unroll
                for (int nt = 0; nt < 4; nt++)
                    H[rowoff + nt * 16] = (_Float16)gelu_tanh(acc[mt][nt][i]);
            }
        }
    }
}

// GEMM2 split-K half: O[row, :] = H[row, kh..kh+2047] @ W2[e][kh..][:]. Pure GEMM, plain stores.
__global__ __launch_bounds__(256) void k_gemm2(
    const _Float16* __restrict__ H, const _Float16* __restrict__ BT,
    const int* __restrict__ counts, const int* __restrict__ base,
    float* __restrict__ O, int kh) {
    int e = blockIdx.z;
    int cnt = counts[e];
    int p0 = blockIdx.y * 128;
    if (p0 >= cnt) return;
    int n0 = blockIdx.x * 128;
    const _Float16* B = BT + (size_t)e * 4194304;   // [1024 n][4096 k]
    int rowbase = base[e];

    __shared__ _Float16 As[128 * 32];
    __shared__ _Float16 Bs[128 * 32];

    int tid = threadIdx.x;
    int w = tid >> 6, lane = tid & 63;
    int c0 = tid, c1 = tid + 256;
    int r0 = rowbase + min(p0 + (c0 >> 2), cnt - 1);
    int r1 = rowbase + min(p0 + (c1 >> 2), cnt - 1);
    const _Float16* pA0 = H + (size_t)r0 * DFF + kh + (c0 & 3) * 8;
    const _Float16* pA1 = H + (size_t)r1 * DFF + kh + (c1 & 3) * 8;
    const _Float16* pB0 = B + (size_t)(n0 + (c0 >> 2)) * 4096 + kh + (c0 & 3) * 8;
    const _Float16* pB1 = B + (size_t)(n0 + (c1 >> 2)) * 4096 + kh + (c1 & 3) * 8;
    _Float16* ldsA0 = As + (w * 64) * 8;
    _Float16* ldsA1 = As + (256 + w * 64) * 8;
    _Float16* ldsB0 = Bs + (w * 64) * 8;
    _Float16* ldsB1 = Bs + (256 + w * 64) * 8;

    int wm = w >> 1, wn = w & 1;
    int lhi = lane >> 4, llo = lane & 15;
    const _Float16* arp = As + ((wm * 64 + llo) * 32 + lhi * 8);
    const _Float16* brp = Bs + ((wn * 64 + llo) * 32 + lhi * 8);

    f32x4 acc[4][4] = {};
    for (int k0 = 0; k0 < 2048; k0 += 32) {
        __syncthreads();
        gll(pA0, ldsA0); gll(pA1, ldsA1);
        gll(pB0, ldsB0); gll(pB1, ldsB1);
        pA0 += 32; pA1 += 32; pB0 += 32; pB1 += 32;
        __syncthreads();
        f16x8 a[4], b[4];
#pragma unroll
        for (int i = 0; i < 4; i++) {
            a[i] = *(const f16x8*)(arp + i * 512);
            b[i] = *(const f16x8*)(brp + i * 512);
        }
#pragma unroll
        for (int mt = 0; mt < 4; mt++)
#pragma unroll
            for (int nt = 0; nt < 4; nt++)
                acc[mt][nt] = __builtin_amdgcn_mfma_f32_16x16x32_f16(a[mt], b[nt], acc[mt][nt], 0, 0, 0);
    }

#pragma unroll
    for (int mt = 0; mt < 4; mt++) {
#pragma unroll
        for (int i = 0; i < 4; i++) {
            int p = p0 + wm * 64 + mt * 16 + lhi * 4 + i;
            if (p < cnt) {
                size_t o = (size_t)(rowbase + p) * D_EMB + n0 + wn * 64 + llo;
#pragma unroll
                for (int nt = 0; nt < 4; nt++)
                    O[o + nt * 16] = acc[mt][nt][i];
            }
        }
    }
}

// out[t,:] = w0*(O0[r0]+O1[r0]) + w1*(O0[r1]+O1[r1])
__global__ __launch_bounds__(256) void k_final(
    const float* __restrict__ O0, const float* __restrict__ O1,
    const int* __restrict__ base,
    const int* __restrict__ tok_e, const int* __restrict__ tok_p,
    const float* __restrict__ tok_w, float* __restrict__ out) {
    int t = blockIdx.x;
    int r0 = base[tok_e[t * 2 + 0]] + tok_p[t * 2 + 0];
    int r1 = base[tok_e[t * 2 + 1]] + tok_p[t * 2 + 1];
    float w0 = tok_w[t * 2 + 0], w1 = tok_w[t * 2 + 1];
    int i = threadIdx.x * 4;
    float4 a0 = *(const float4*)(O0 + (size_t)r0 * D_EMB + i);
    float4 b0 = *(const float4*)(O1 + (size_t)r0 * D_EMB + i);
    float4 a1 = *(const float4*)(O0 + (size_t)r1 * D_EMB + i);
    float4 b1 = *(const float4*)(O1 + (size_t)r1 * D_EMB + i);
    float4 o;
    o.x = w0 * (a0.x + b0.x) + w1 * (a1.x + b1.x);
    o.y = w0 * (a0.y + b0.y) + w1 * (a1.y + b1.y);
    o.z = w0 * (a0.z + b0.z) + w1 * (a1.z + b1.z);
    o.w = w0 * (a0.w + b0.w) + w1 * (a1.w + b1.w);
    *(float4*)(out + (size_t)t * D_EMB + i) = o;
}

extern "C" void kernel_launch(void* const* d_in, const int* in_sizes, int n_in,
                              void* d_out, int out_size, void* d_ws, size_t ws_size,
                              hipStream_t stream) {
    const float* x    = (const float*)d_in[0];
    const float* mask = (const float*)d_in[1];
    const float* Wr   = (const float*)d_in[2];
    const float* W1   = (const float*)d_in[3];   // [8,1024,4096]
    const float* W2   = (const float*)d_in[4];   // [8,4096,1024]
    float* out = (float*)d_out;

    // ws layout (~200 MB of the 512 MiB workspace)
    char* ws = (char*)d_ws;
    const size_t MB = 1024 * 1024;
    int*      counts = (int*)(ws + 0);
    int*      base   = (int*)(ws + 256);
    int*      elist  = (int*)(ws + 1024);            // 8*2048 ints (64KB)
    int*      tok_e  = (int*)(ws + 1024 + 65536);    // 2*2048
    int*      tok_p  = (int*)(ws + 1024 + 65536 + 16384);
    float*    tok_w  = (float*)(ws + 1024 + 65536 + 32768);
    _Float16* xh     = (_Float16*)(ws + 1 * MB);     // 4 MB
    _Float16* W1T    = (_Float16*)(ws + 8 * MB);     // 64 MB  [e][4096 n][1024 k]
    _Float16* W2T    = (_Float16*)(ws + 72 * MB);    // 64 MB  [e][1024 n][4096 k]
    _Float16* H      = (_Float16*)(ws + 136 * MB);   // 32 MB  [4096][4096]
    float*    O0     = (float*)(ws + 168 * MB);      // 16 MB  [4096][1024]
    float*    O1     = (float*)(ws + 184 * MB);      // 16 MB

    k_zero<<<1, 64, 0, stream>>>(counts);
    k_router<<<T_TOK / 4, 256, 0, stream>>>(x, mask, Wr, counts, elist, tok_e, tok_p, tok_w);
    k_prefix<<<1, 64, 0, stream>>>(counts, base);
    k_cvt_x<<<T_TOK * D_EMB / 4 / 256, 256, 0, stream>>>((const float4*)x, xh);
    k_transpose<<<dim3(64, 16, NE), 256, 0, stream>>>(W1, W1T, DFF, 1024);   // W1: K=1024,N=4096
    k_transpose<<<dim3(16, 64, NE), 256, 0, stream>>>(W2, W2T, D_EMB, 4096); // W2: K=4096,N=1024

    k_gemm1<<<dim3(32, 16, NE), 256, 0, stream>>>(xh, W1T, counts, base, elist, H);
    k_gemm2<<<dim3(8, 16, NE), 256, 0, stream>>>(H, W2T, counts, base, O0, 0);
    k_gemm2<<<dim3(8, 16, NE), 256, 0, stream>>>(H, W2T, counts, base, O1, 2048);
    k_final<<<T_TOK, 256, 0, stream>>>(O0, O1, base, tok_e, tok_p, tok_w, out);
}

// Round 4
// 506.775 us; speedup vs baseline: 2.8906x; 1.0721x over previous
//
#include <hip/hip_runtime.h>
#include <hip/hip_bf16.h>

// MaskedMoE: T=2048, d=1024, d_ff=4096, E=8, top-2.
// R3: XOR-swizzled LDS staging (conflict-free ds_read_b128 under global_load_lds's
// fixed lane->slot mapping), BK=64 (32 MFMA/barrier), GEMM2 split-K=4 in one
// dispatch (4 O buffers, no atomics), router+cvt fused, prefix inlined. 6 launches.

#define T_TOK 2048
#define D_EMB 1024
#define DFF   4096
#define NE    8

typedef _Float16 f16x8 __attribute__((ext_vector_type(8)));
typedef float    f32x4 __attribute__((ext_vector_type(4)));

__device__ __forceinline__ float gelu_tanh(float x) {
    const float c = 0.7978845608028654f;
    float z = c * (x + 0.044715f * x * x * x);
    float u = __expf(2.0f * z);
    return 0.5f * x * (1.0f + (u - 1.0f) / (u + 1.0f));
}

__device__ __forceinline__ void gll(const void* g, void* l) {
    __builtin_amdgcn_global_load_lds((__attribute__((address_space(1))) void*)g,
                                     (__attribute__((address_space(3))) void*)l,
                                     16, 0, 0);
}

__global__ void k_zero(int* counts) {
    if (threadIdx.x < NE) counts[threadIdx.x] = 0;
}

// Router (one wave/token) + fp16 conversion of x fused.
__global__ __launch_bounds__(256) void k_router(
    const float* __restrict__ x, const float* __restrict__ mask,
    const float* __restrict__ Wr, _Float16* __restrict__ xh,
    int* __restrict__ counts, int* __restrict__ elist,
    int* __restrict__ tok_e, int* __restrict__ tok_p, float* __restrict__ tok_w) {
    int wave = threadIdx.x >> 6;
    int lane = threadIdx.x & 63;
    int t = blockIdx.x * 4 + wave;
    if (t >= T_TOK) return;

    float acc[NE];
#pragma unroll
    for (int e = 0; e < NE; e++) acc[e] = 0.f;
    const float* xr = x + (size_t)t * D_EMB;
    for (int c = 0; c < D_EMB / 64; c++) {
        int i = c * 64 + lane;
        float xv = xr[i];
        xh[(size_t)t * D_EMB + i] = (_Float16)xv;   // fused cvt
        const float* wr = Wr + (size_t)i * NE;
#pragma unroll
        for (int e = 0; e < NE; e++) acc[e] += xv * wr[e];
    }
#pragma unroll
    for (int e = 0; e < NE; e++) {
#pragma unroll
        for (int off = 32; off > 0; off >>= 1)
            acc[e] += __shfl_xor(acc[e], off);
    }
    if (lane == 0) {
        float p[NE];
        float mx = -1e30f;
#pragma unroll
        for (int e = 0; e < NE; e++) {
            p[e] = acc[e] * mask[t * NE + e];
            mx = fmaxf(mx, p[e]);
        }
        float s = 0.f;
#pragma unroll
        for (int e = 0; e < NE; e++) { p[e] = expf(p[e] - mx); s += p[e]; }
#pragma unroll
        for (int e = 0; e < NE; e++) p[e] /= s;
        int e0 = 0; float b0 = p[0];
#pragma unroll
        for (int e = 1; e < NE; e++) if (p[e] > b0) { b0 = p[e]; e0 = e; }
        int e1 = -1; float b1 = -1.f;
#pragma unroll
        for (int e = 0; e < NE; e++) if (e != e0 && p[e] > b1) { b1 = p[e]; e1 = e; }

        int pos0 = atomicAdd(&counts[e0], 1);
        elist[e0 * T_TOK + pos0] = t;
        tok_e[t * 2 + 0] = e0; tok_p[t * 2 + 0] = pos0; tok_w[t * 2 + 0] = b0;
        int pos1 = atomicAdd(&counts[e1], 1);
        elist[e1 * T_TOK + pos1] = t;
        tok_e[t * 2 + 1] = e1; tok_p[t * 2 + 1] = pos1; tok_w[t * 2 + 1] = b1;
    }
}

// Merged transpose: z<8 -> W1 expert z ([1024][4096] -> [4096][1024] fp16),
//                   z>=8 -> W2 expert z-8 ([4096][1024] -> [1024][4096] fp16).
__global__ __launch_bounds__(256) void k_transpose(
    const float* __restrict__ W1, const float* __restrict__ W2,
    _Float16* __restrict__ W1T, _Float16* __restrict__ W2T) {
    __shared__ float tile[64][65];
    int bz = blockIdx.z;
    int e = bz & 7;
    bool isW2 = bz >= 8;
    const float* S = (isW2 ? W2 : W1) + (size_t)e * 4194304;
    _Float16* D = (isW2 ? W2T : W1T) + (size_t)e * 4194304;
    int src_ld = isW2 ? 1024 : 4096;
    int dst_ld = isW2 ? 4096 : 1024;
    int bx = blockIdx.x;
    int nb, kb;
    if (isW2) { nb = (bx & 15) * 64; kb = (bx >> 4) * 64; }
    else      { nb = (bx & 63) * 64; kb = (bx >> 6) * 64; }
    int t = threadIdx.x;
#pragma unroll
    for (int i = 0; i < 4; i++) {
        int r = (t >> 4) + i * 16;
        int c = (t & 15) * 4;
        float4 v = *(const float4*)(S + (size_t)(kb + r) * src_ld + nb + c);
        tile[r][c + 0] = v.x; tile[r][c + 1] = v.y;
        tile[r][c + 2] = v.z; tile[r][c + 3] = v.w;
    }
    __syncthreads();
#pragma unroll
    for (int j = 0; j < 2; j++) {
        int idx = j * 256 + t;
        int n = idx >> 3, kc = idx & 7;
        f16x8 o;
#pragma unroll
        for (int u = 0; u < 8; u++) o[u] = (_Float16)tile[kc * 8 + u][n];
        *(f16x8*)(D + (size_t)(nb + n) * dst_ld + kb + kc * 8) = o;
    }
}

// ---- shared GEMM core helpers -----------------------------------------------
// LDS tile: 128 rows x 8 chunks x 8 f16. slot(row,kc) holds global chunk
// kc^(row&7). Producer: slot s=q*256+tid -> row=s>>3, data chunk=(tid&7)^((tid>>3)&7).
// Consumer: chunk d of row r lives at elem offset r*64 + (d^(r&7))*8.

// GEMM1: H[rowbase+p, :] = gelu(xh[elist[e,p], :] @ W1T[e]^T). K=1024, 16 iters.
__global__ __launch_bounds__(256) void k_gemm1(
    const _Float16* __restrict__ xh, const _Float16* __restrict__ BT,
    const int* __restrict__ counts, const int* __restrict__ elist,
    _Float16* __restrict__ H) {
    int e = blockIdx.z;
    int cnt = counts[e];
    int p0 = blockIdx.y * 128;
    if (p0 >= cnt) return;
    int rowbase = 0;
    for (int i = 0; i < NE; i++) rowbase += (i < e) ? counts[i] : 0;
    int n0 = blockIdx.x * 128;
    const _Float16* B = BT + (size_t)e * 4194304;   // [4096 n][1024 k]

    __shared__ _Float16 As[128 * 64];
    __shared__ _Float16 Bs[128 * 64];
    __shared__ int ttok[128];

    int tid = threadIdx.x;
    if (tid < 128) ttok[tid] = elist[e * T_TOK + min(p0 + tid, cnt - 1)];
    __syncthreads();

    int w = tid >> 6, lane = tid & 63;
    int rq = tid >> 3;                       // base row (q adds 32)
    int cch = (tid & 7) ^ ((tid >> 3) & 7);  // swizzled source chunk
    const _Float16* pA[4];
    const _Float16* pB[4];
    _Float16* lA[4];
    _Float16* lB[4];
#pragma unroll
    for (int q = 0; q < 4; q++) {
        int row = q * 32 + rq;
        pA[q] = xh + (size_t)ttok[row] * D_EMB + cch * 8;
        pB[q] = B + (size_t)(n0 + row) * 1024 + cch * 8;
        lA[q] = As + (q * 256 + w * 64) * 8;
        lB[q] = Bs + (q * 256 + w * 64) * 8;
    }

    int wm = w >> 1, wn = w & 1;
    int lhi = lane >> 4, llo = lane & 15;
    int m7 = llo & 7;
    int kc0 = lhi ^ m7, kc1 = kc0 ^ 4;
    const _Float16* arp0 = As + (wm * 64 + llo) * 64 + kc0 * 8;
    const _Float16* arp1 = As + (wm * 64 + llo) * 64 + kc1 * 8;
    const _Float16* brp0 = Bs + (wn * 64 + llo) * 64 + kc0 * 8;
    const _Float16* brp1 = Bs + (wn * 64 + llo) * 64 + kc1 * 8;

    f32x4 acc[4][4] = {};
    for (int it = 0; it < 16; ++it) {
        __syncthreads();
#pragma unroll
        for (int q = 0; q < 4; q++) { gll(pA[q], lA[q]); gll(pB[q], lB[q]); }
#pragma unroll
        for (int q = 0; q < 4; q++) { pA[q] += 64; pB[q] += 64; }
        __syncthreads();
        f16x8 a[4], b[4];
#pragma unroll
        for (int i = 0; i < 4; i++) {
            a[i] = *(const f16x8*)(arp0 + i * 1024);
            b[i] = *(const f16x8*)(brp0 + i * 1024);
        }
#pragma unroll
        for (int mt = 0; mt < 4; mt++)
#pragma unroll
            for (int nt = 0; nt < 4; nt++)
                acc[mt][nt] = __builtin_amdgcn_mfma_f32_16x16x32_f16(a[mt], b[nt], acc[mt][nt], 0, 0, 0);
#pragma unroll
        for (int i = 0; i < 4; i++) {
            a[i] = *(const f16x8*)(arp1 + i * 1024);
            b[i] = *(const f16x8*)(brp1 + i * 1024);
        }
#pragma unroll
        for (int mt = 0; mt < 4; mt++)
#pragma unroll
            for (int nt = 0; nt < 4; nt++)
                acc[mt][nt] = __builtin_amdgcn_mfma_f32_16x16x32_f16(a[mt], b[nt], acc[mt][nt], 0, 0, 0);
    }

#pragma unroll
    for (int mt = 0; mt < 4; mt++) {
#pragma unroll
        for (int i = 0; i < 4; i++) {
            int p = p0 + wm * 64 + mt * 16 + lhi * 4 + i;
            if (p < cnt) {
                size_t rowoff = (size_t)(rowbase + p) * DFF + n0 + wn * 64 + llo;
#pragma unroll
                for (int nt = 0; nt < 4; nt++)
                    H[rowoff + nt * 16] = (_Float16)gelu_tanh(acc[mt][nt][i]);
            }
        }
    }
}

// GEMM2 split-K=4: O[sp][row, :] = H[row, sp*1024..+1024] @ W2T[e][:, same k]. 16 iters.
__global__ __launch_bounds__(256) void k_gemm2(
    const _Float16* __restrict__ H, const _Float16* __restrict__ BT,
    const int* __restrict__ counts, float* __restrict__ Obase) {
    int bz = blockIdx.z;
    int e = bz & 7, sp = bz >> 3;
    int cnt = counts[e];
    int p0 = blockIdx.y * 128;
    if (p0 >= cnt) return;
    int rowbase = 0;
    for (int i = 0; i < NE; i++) rowbase += (i < e) ? counts[i] : 0;
    int n0 = blockIdx.x * 128;
    int kh = sp * 1024;
    const _Float16* B = BT + (size_t)e * 4194304;   // [1024 n][4096 k]
    float* O = Obase + (size_t)sp * 4194304;

    __shared__ _Float16 As[128 * 64];
    __shared__ _Float16 Bs[128 * 64];

    int tid = threadIdx.x;
    int w = tid >> 6, lane = tid & 63;
    int rq = tid >> 3;
    int cch = (tid & 7) ^ ((tid >> 3) & 7);
    const _Float16* pA[4];
    const _Float16* pB[4];
    _Float16* lA[4];
    _Float16* lB[4];
#pragma unroll
    for (int q = 0; q < 4; q++) {
        int row = q * 32 + rq;
        int r = rowbase + min(p0 + row, cnt - 1);
        pA[q] = H + (size_t)r * DFF + kh + cch * 8;
        pB[q] = B + (size_t)(n0 + row) * 4096 + kh + cch * 8;
        lA[q] = As + (q * 256 + w * 64) * 8;
        lB[q] = Bs + (q * 256 + w * 64) * 8;
    }

    int wm = w >> 1, wn = w & 1;
    int lhi = lane >> 4, llo = lane & 15;
    int m7 = llo & 7;
    int kc0 = lhi ^ m7, kc1 = kc0 ^ 4;
    const _Float16* arp0 = As + (wm * 64 + llo) * 64 + kc0 * 8;
    const _Float16* arp1 = As + (wm * 64 + llo) * 64 + kc1 * 8;
    const _Float16* brp0 = Bs + (wn * 64 + llo) * 64 + kc0 * 8;
    const _Float16* brp1 = Bs + (wn * 64 + llo) * 64 + kc1 * 8;

    f32x4 acc[4][4] = {};
    for (int it = 0; it < 16; ++it) {
        __syncthreads();
#pragma unroll
        for (int q = 0; q < 4; q++) { gll(pA[q], lA[q]); gll(pB[q], lB[q]); }
#pragma unroll
        for (int q = 0; q < 4; q++) { pA[q] += 64; pB[q] += 64; }
        __syncthreads();
        f16x8 a[4], b[4];
#pragma unroll
        for (int i = 0; i < 4; i++) {
            a[i] = *(const f16x8*)(arp0 + i * 1024);
            b[i] = *(const f16x8*)(brp0 + i * 1024);
        }
#pragma unroll
        for (int mt = 0; mt < 4; mt++)
#pragma unroll
            for (int nt = 0; nt < 4; nt++)
                acc[mt][nt] = __builtin_amdgcn_mfma_f32_16x16x32_f16(a[mt], b[nt], acc[mt][nt], 0, 0, 0);
#pragma unroll
        for (int i = 0; i < 4; i++) {
            a[i] = *(const f16x8*)(arp1 + i * 1024);
            b[i] = *(const f16x8*)(brp1 + i * 1024);
        }
#pragma unroll
        for (int mt = 0; mt < 4; mt++)
#pragma unroll
            for (int nt = 0; nt < 4; nt++)
                acc[mt][nt] = __builtin_amdgcn_mfma_f32_16x16x32_f16(a[mt], b[nt], acc[mt][nt], 0, 0, 0);
    }

#pragma unroll
    for (int mt = 0; mt < 4; mt++) {
#pragma unroll
        for (int i = 0; i < 4; i++) {
            int p = p0 + wm * 64 + mt * 16 + lhi * 4 + i;
            if (p < cnt) {
                size_t o = (size_t)(rowbase + p) * D_EMB + n0 + wn * 64 + llo;
#pragma unroll
                for (int nt = 0; nt < 4; nt++)
                    O[o + nt * 16] = acc[mt][nt][i];
            }
        }
    }
}

// out[t,:] = w0*sum_sp Osp[r0] + w1*sum_sp Osp[r1]
__global__ __launch_bounds__(256) void k_final(
    const float* __restrict__ Obase, const int* __restrict__ counts,
    const int* __restrict__ tok_e, const int* __restrict__ tok_p,
    const float* __restrict__ tok_w, float* __restrict__ out) {
    __shared__ int sb[NE];
    int t = blockIdx.x;
    if (threadIdx.x == 0) {
        int s = 0;
        for (int e = 0; e < NE; e++) { sb[e] = s; s += counts[e]; }
    }
    __syncthreads();
    int r0 = sb[tok_e[t * 2 + 0]] + tok_p[t * 2 + 0];
    int r1 = sb[tok_e[t * 2 + 1]] + tok_p[t * 2 + 1];
    float w0 = tok_w[t * 2 + 0], w1 = tok_w[t * 2 + 1];
    int i = threadIdx.x * 4;
    float4 s0 = {0, 0, 0, 0}, s1 = {0, 0, 0, 0};
#pragma unroll
    for (int sp = 0; sp < 4; sp++) {
        const float* O = Obase + (size_t)sp * 4194304;
        float4 a = *(const float4*)(O + (size_t)r0 * D_EMB + i);
        float4 b = *(const float4*)(O + (size_t)r1 * D_EMB + i);
        s0.x += a.x; s0.y += a.y; s0.z += a.z; s0.w += a.w;
        s1.x += b.x; s1.y += b.y; s1.z += b.z; s1.w += b.w;
    }
    float4 o;
    o.x = w0 * s0.x + w1 * s1.x;
    o.y = w0 * s0.y + w1 * s1.y;
    o.z = w0 * s0.z + w1 * s1.z;
    o.w = w0 * s0.w + w1 * s1.w;
    *(float4*)(out + (size_t)t * D_EMB + i) = o;
}

extern "C" void kernel_launch(void* const* d_in, const int* in_sizes, int n_in,
                              void* d_out, int out_size, void* d_ws, size_t ws_size,
                              hipStream_t stream) {
    const float* x    = (const float*)d_in[0];
    const float* mask = (const float*)d_in[1];
    const float* Wr   = (const float*)d_in[2];
    const float* W1   = (const float*)d_in[3];   // [8,1024,4096]
    const float* W2   = (const float*)d_in[4];   // [8,4096,1024]
    float* out = (float*)d_out;

    char* ws = (char*)d_ws;
    const size_t MB = 1024 * 1024;
    int*      counts = (int*)(ws + 0);
    int*      elist  = (int*)(ws + 1024);
    int*      tok_e  = (int*)(ws + 1024 + 65536);
    int*      tok_p  = (int*)(ws + 1024 + 65536 + 16384);
    float*    tok_w  = (float*)(ws + 1024 + 65536 + 32768);
    _Float16* xh     = (_Float16*)(ws + 1 * MB);    // 4 MB
    _Float16* W1T    = (_Float16*)(ws + 8 * MB);    // 64 MB  [e][4096 n][1024 k]
    _Float16* W2T    = (_Float16*)(ws + 72 * MB);   // 64 MB  [e][1024 n][4096 k]
    _Float16* H      = (_Float16*)(ws + 136 * MB);  // 32 MB  [4096][4096]
    float*    Obuf   = (float*)(ws + 168 * MB);     // 64 MB  [4 sp][4096][1024]

    k_zero<<<1, 64, 0, stream>>>(counts);
    k_router<<<T_TOK / 4, 256, 0, stream>>>(x, mask, Wr, xh, counts, elist, tok_e, tok_p, tok_w);
    k_transpose<<<dim3(1024, 1, 16), 256, 0, stream>>>(W1, W2, W1T, W2T);
    k_gemm1<<<dim3(32, 16, NE), 256, 0, stream>>>(xh, W1T, counts, elist, H);
    k_gemm2<<<dim3(8, 16, 32), 256, 0, stream>>>(H, W2T, counts, Obuf);
    k_final<<<T_TOK, 256, 0, stream>>>(Obuf, counts, tok_e, tok_p, tok_w, out);
}

// Round 5
// 495.844 us; speedup vs baseline: 2.9543x; 1.0220x over previous
//
#include <hip/hip_runtime.h>
#include <hip/hip_bf16.h>

// MaskedMoE: T=2048, d=1024, d_ff=4096, E=8, top-2.
// R4: tiled+pre-swizzled transposed weights.
//   WT layout: [e][kt][n][64 k], each (kt, n-row) = 128B with 16B chunks stored at
//   position c^(n&7). GEMM B-staging becomes identity-contiguous global_load_lds
//   (16KB/iter); consumer reads identical to R3 (kc0 = lhi^(llo&7)).
//   Transpose: 64k x 128n fp32 tile, 8 indep float4 loads/thread, padded+swizzled
//   LDS (2-way max on column reads), contiguous 16KB tiled writes.

#define T_TOK 2048
#define D_EMB 1024
#define DFF   4096
#define NE    8

typedef _Float16 f16x8 __attribute__((ext_vector_type(8)));
typedef float    f32x4 __attribute__((ext_vector_type(4)));

__device__ __forceinline__ float gelu_tanh(float x) {
    const float c = 0.7978845608028654f;
    float z = c * (x + 0.044715f * x * x * x);
    float u = __expf(2.0f * z);
    return 0.5f * x * (1.0f + (u - 1.0f) / (u + 1.0f));
}

__device__ __forceinline__ void gll(const void* g, void* l) {
    __builtin_amdgcn_global_load_lds((__attribute__((address_space(1))) void*)g,
                                     (__attribute__((address_space(3))) void*)l,
                                     16, 0, 0);
}

__global__ void k_zero(int* counts) {
    if (threadIdx.x < NE) counts[threadIdx.x] = 0;
}

// Router (one wave/token) + fp16 conversion of x fused.
__global__ __launch_bounds__(256) void k_router(
    const float* __restrict__ x, const float* __restrict__ mask,
    const float* __restrict__ Wr, _Float16* __restrict__ xh,
    int* __restrict__ counts, int* __restrict__ elist,
    int* __restrict__ tok_e, int* __restrict__ tok_p, float* __restrict__ tok_w) {
    int wave = threadIdx.x >> 6;
    int lane = threadIdx.x & 63;
    int t = blockIdx.x * 4 + wave;
    if (t >= T_TOK) return;

    float acc[NE];
#pragma unroll
    for (int e = 0; e < NE; e++) acc[e] = 0.f;
    const float* xr = x + (size_t)t * D_EMB;
    for (int c = 0; c < D_EMB / 64; c++) {
        int i = c * 64 + lane;
        float xv = xr[i];
        xh[(size_t)t * D_EMB + i] = (_Float16)xv;
        const float* wr = Wr + (size_t)i * NE;
#pragma unroll
        for (int e = 0; e < NE; e++) acc[e] += xv * wr[e];
    }
#pragma unroll
    for (int e = 0; e < NE; e++) {
#pragma unroll
        for (int off = 32; off > 0; off >>= 1)
            acc[e] += __shfl_xor(acc[e], off);
    }
    if (lane == 0) {
        float p[NE];
        float mx = -1e30f;
#pragma unroll
        for (int e = 0; e < NE; e++) {
            p[e] = acc[e] * mask[t * NE + e];
            mx = fmaxf(mx, p[e]);
        }
        float s = 0.f;
#pragma unroll
        for (int e = 0; e < NE; e++) { p[e] = expf(p[e] - mx); s += p[e]; }
#pragma unroll
        for (int e = 0; e < NE; e++) p[e] /= s;
        int e0 = 0; float b0 = p[0];
#pragma unroll
        for (int e = 1; e < NE; e++) if (p[e] > b0) { b0 = p[e]; e0 = e; }
        int e1 = -1; float b1 = -1.f;
#pragma unroll
        for (int e = 0; e < NE; e++) if (e != e0 && p[e] > b1) { b1 = p[e]; e1 = e; }

        int pos0 = atomicAdd(&counts[e0], 1);
        elist[e0 * T_TOK + pos0] = t;
        tok_e[t * 2 + 0] = e0; tok_p[t * 2 + 0] = pos0; tok_w[t * 2 + 0] = b0;
        int pos1 = atomicAdd(&counts[e1], 1);
        elist[e1 * T_TOK + pos1] = t;
        tok_e[t * 2 + 1] = e1; tok_p[t * 2 + 1] = pos1; tok_w[t * 2 + 1] = b1;
    }
}

// Transpose fp32 [K][N] -> tiled-swizzled fp16 [kt][n][64k].
// z<8: W1 expert z (K=1024,N=4096, plane stride 262144, 16 kt x 32 nb)
// z>=8: W2 expert z-8 (K=4096,N=1024, plane stride 65536, 64 kt x 8 nb)
__global__ __launch_bounds__(256) void k_transpose(
    const float* __restrict__ W1, const float* __restrict__ W2,
    _Float16* __restrict__ W1T, _Float16* __restrict__ W2T) {
    __shared__ float tile[64 * 132];   // 64 k-rows x 128 n (pad to 132)
    int bz = blockIdx.z;
    int e = bz & 7;
    bool isW2 = bz >= 8;
    const float* S = (isW2 ? W2 : W1) + (size_t)e * 4194304;
    _Float16* Dst = (isW2 ? W2T : W1T) + (size_t)e * 4194304;
    int src_ld   = isW2 ? 1024 : 4096;
    int plane_sz = isW2 ? 65536 : 262144;
    int bx = blockIdx.x;
    int kt, nb;
    if (isW2) { kt = bx >> 3; nb = (bx & 7) * 128; }
    else      { kt = bx >> 5; nb = (bx & 31) * 128; }
    int kb = kt * 64;
    int tid = threadIdx.x;

    // phase 1: read 64 rows x 512B (8 independent float4 per thread), swizzled store
#pragma unroll
    for (int i = 0; i < 8; i++) {
        int f = i * 256 + tid;
        int row = f >> 5;            // 0..63
        int col4 = f & 31;           // float4 index within 128 floats
        float4 v = *(const float4*)(S + (size_t)(kb + row) * src_ld + nb + col4 * 4);
        int col4s = col4 ^ ((row >> 3) & 7);
        *(float4*)(&tile[row * 132 + col4s * 4]) = v;
    }
    __syncthreads();

    // phase 2: column gather -> f16x8 (8 k-consecutive at fixed n), tiled+chunk-swizzled write
    _Float16* plane = Dst + (size_t)kt * plane_sz;
#pragma unroll
    for (int i = 0; i < 4; i++) {
        int idx = i * 256 + tid;
        int n = idx >> 3;            // 0..127
        int c = idx & 7;             // k-chunk
        f16x8 o;
#pragma unroll
        for (int u = 0; u < 8; u++) {
            int k = c * 8 + u;
            int col4s = (n >> 2) ^ ((k >> 3) & 7);
            o[u] = (_Float16)tile[k * 132 + col4s * 4 + (n & 3)];
        }
        *(f16x8*)(plane + (size_t)(nb + n) * 64 + (c ^ (n & 7)) * 8) = o;
    }
}

// ---- GEMM core (R3-proven consumer) -----------------------------------------
// LDS tile: 128 rows x 8 chunks x 8 f16; position p of row r holds chunk p^(r&7).
// A producer: gather rows with per-lane chunk cch=(tid&7)^((tid>>3)&7).
// B producer: identity-contiguous copy of the pre-swizzled weight plane.
// Consumer: kc0 = lhi ^ (llo&7), kc1 = kc0^4.

// GEMM1: H[rowbase+p, :] = gelu(xh[elist[e,p], :] @ W1[e]). K=1024, 16 iters.
__global__ __launch_bounds__(256) void k_gemm1(
    const _Float16* __restrict__ xh, const _Float16* __restrict__ BT,
    const int* __restrict__ counts, const int* __restrict__ elist,
    _Float16* __restrict__ H) {
    int e = blockIdx.z;
    int cnt = counts[e];
    int p0 = blockIdx.y * 128;
    if (p0 >= cnt) return;
    int rowbase = 0;
    for (int i = 0; i < NE; i++) rowbase += (i < e) ? counts[i] : 0;
    int n0 = blockIdx.x * 128;
    const _Float16* B = BT + (size_t)e * 4194304;   // tiled: [kt16][4096][64]

    __shared__ _Float16 As[128 * 64];
    __shared__ _Float16 Bs[128 * 64];
    __shared__ int ttok[128];

    int tid = threadIdx.x;
    if (tid < 128) ttok[tid] = elist[e * T_TOK + min(p0 + tid, cnt - 1)];
    __syncthreads();

    int w = tid >> 6, lane = tid & 63;
    int rq = tid >> 3;
    int cch = (tid & 7) ^ ((tid >> 3) & 7);
    const _Float16* pA[4];
    const _Float16* pB[4];
    _Float16* lA[4];
    _Float16* lB[4];
#pragma unroll
    for (int q = 0; q < 4; q++) {
        int row = q * 32 + rq;
        pA[q] = xh + (size_t)ttok[row] * D_EMB + cch * 8;
        pB[q] = B + (size_t)n0 * 64 + (q * 256 + tid) * 8;   // contiguous 16KB plane slice
        lA[q] = As + (q * 256 + w * 64) * 8;
        lB[q] = Bs + (q * 256 + w * 64) * 8;
    }

    int wm = w >> 1, wn = w & 1;
    int lhi = lane >> 4, llo = lane & 15;
    int m7 = llo & 7;
    int kc0 = lhi ^ m7, kc1 = kc0 ^ 4;
    const _Float16* arp0 = As + (wm * 64 + llo) * 64 + kc0 * 8;
    const _Float16* arp1 = As + (wm * 64 + llo) * 64 + kc1 * 8;
    const _Float16* brp0 = Bs + (wn * 64 + llo) * 64 + kc0 * 8;
    const _Float16* brp1 = Bs + (wn * 64 + llo) * 64 + kc1 * 8;

    f32x4 acc[4][4] = {};
    for (int it = 0; it < 16; ++it) {
        __syncthreads();
#pragma unroll
        for (int q = 0; q < 4; q++) { gll(pA[q], lA[q]); gll(pB[q], lB[q]); }
#pragma unroll
        for (int q = 0; q < 4; q++) { pA[q] += 64; pB[q] += 262144; }
        __syncthreads();
        f16x8 a[4], b[4];
#pragma unroll
        for (int i = 0; i < 4; i++) {
            a[i] = *(const f16x8*)(arp0 + i * 1024);
            b[i] = *(const f16x8*)(brp0 + i * 1024);
        }
#pragma unroll
        for (int mt = 0; mt < 4; mt++)
#pragma unroll
            for (int nt = 0; nt < 4; nt++)
                acc[mt][nt] = __builtin_amdgcn_mfma_f32_16x16x32_f16(a[mt], b[nt], acc[mt][nt], 0, 0, 0);
#pragma unroll
        for (int i = 0; i < 4; i++) {
            a[i] = *(const f16x8*)(arp1 + i * 1024);
            b[i] = *(const f16x8*)(brp1 + i * 1024);
        }
#pragma unroll
        for (int mt = 0; mt < 4; mt++)
#pragma unroll
            for (int nt = 0; nt < 4; nt++)
                acc[mt][nt] = __builtin_amdgcn_mfma_f32_16x16x32_f16(a[mt], b[nt], acc[mt][nt], 0, 0, 0);
    }

#pragma unroll
    for (int mt = 0; mt < 4; mt++) {
#pragma unroll
        for (int i = 0; i < 4; i++) {
            int p = p0 + wm * 64 + mt * 16 + lhi * 4 + i;
            if (p < cnt) {
                size_t rowoff = (size_t)(rowbase + p) * DFF + n0 + wn * 64 + llo;
#pragma unroll
                for (int nt = 0; nt < 4; nt++)
                    H[rowoff + nt * 16] = (_Float16)gelu_tanh(acc[mt][nt][i]);
            }
        }
    }
}

// GEMM2 split-K=4: O[sp][row, :] = H[row, sp*1024..+1024] @ W2[e][same k][:]. 16 iters.
__global__ __launch_bounds__(256) void k_gemm2(
    const _Float16* __restrict__ H, const _Float16* __restrict__ BT,
    const int* __restrict__ counts, float* __restrict__ Obase) {
    int bz = blockIdx.z;
    int e = bz & 7, sp = bz >> 3;
    int cnt = counts[e];
    int p0 = blockIdx.y * 128;
    if (p0 >= cnt) return;
    int rowbase = 0;
    for (int i = 0; i < NE; i++) rowbase += (i < e) ? counts[i] : 0;
    int n0 = blockIdx.x * 128;
    int kh = sp * 1024;
    const _Float16* B = BT + (size_t)e * 4194304;   // tiled: [kt64][1024][64]
    float* O = Obase + (size_t)sp * 4194304;

    __shared__ _Float16 As[128 * 64];
    __shared__ _Float16 Bs[128 * 64];

    int tid = threadIdx.x;
    int w = tid >> 6, lane = tid & 63;
    int rq = tid >> 3;
    int cch = (tid & 7) ^ ((tid >> 3) & 7);
    const _Float16* pA[4];
    const _Float16* pB[4];
    _Float16* lA[4];
    _Float16* lB[4];
#pragma unroll
    for (int q = 0; q < 4; q++) {
        int row = q * 32 + rq;
        int r = rowbase + min(p0 + row, cnt - 1);
        pA[q] = H + (size_t)r * DFF + kh + cch * 8;
        pB[q] = B + (size_t)(sp * 16) * 65536 + (size_t)n0 * 64 + (q * 256 + tid) * 8;
        lA[q] = As + (q * 256 + w * 64) * 8;
        lB[q] = Bs + (q * 256 + w * 64) * 8;
    }

    int wm = w >> 1, wn = w & 1;
    int lhi = lane >> 4, llo = lane & 15;
    int m7 = llo & 7;
    int kc0 = lhi ^ m7, kc1 = kc0 ^ 4;
    const _Float16* arp0 = As + (wm * 64 + llo) * 64 + kc0 * 8;
    const _Float16* arp1 = As + (wm * 64 + llo) * 64 + kc1 * 8;
    const _Float16* brp0 = Bs + (wn * 64 + llo) * 64 + kc0 * 8;
    const _Float16* brp1 = Bs + (wn * 64 + llo) * 64 + kc1 * 8;

    f32x4 acc[4][4] = {};
    for (int it = 0; it < 16; ++it) {
        __syncthreads();
#pragma unroll
        for (int q = 0; q < 4; q++) { gll(pA[q], lA[q]); gll(pB[q], lB[q]); }
#pragma unroll
        for (int q = 0; q < 4; q++) { pA[q] += 64; pB[q] += 65536; }
        __syncthreads();
        f16x8 a[4], b[4];
#pragma unroll
        for (int i = 0; i < 4; i++) {
            a[i] = *(const f16x8*)(arp0 + i * 1024);
            b[i] = *(const f16x8*)(brp0 + i * 1024);
        }
#pragma unroll
        for (int mt = 0; mt < 4; mt++)
#pragma unroll
            for (int nt = 0; nt < 4; nt++)
                acc[mt][nt] = __builtin_amdgcn_mfma_f32_16x16x32_f16(a[mt], b[nt], acc[mt][nt], 0, 0, 0);
#pragma unroll
        for (int i = 0; i < 4; i++) {
            a[i] = *(const f16x8*)(arp1 + i * 1024);
            b[i] = *(const f16x8*)(brp1 + i * 1024);
        }
#pragma unroll
        for (int mt = 0; mt < 4; mt++)
#pragma unroll
            for (int nt = 0; nt < 4; nt++)
                acc[mt][nt] = __builtin_amdgcn_mfma_f32_16x16x32_f16(a[mt], b[nt], acc[mt][nt], 0, 0, 0);
    }

#pragma unroll
    for (int mt = 0; mt < 4; mt++) {
#pragma unroll
        for (int i = 0; i < 4; i++) {
            int p = p0 + wm * 64 + mt * 16 + lhi * 4 + i;
            if (p < cnt) {
                size_t o = (size_t)(rowbase + p) * D_EMB + n0 + wn * 64 + llo;
#pragma unroll
                for (int nt = 0; nt < 4; nt++)
                    O[o + nt * 16] = acc[mt][nt][i];
            }
        }
    }
}

// out[t,:] = w0*sum_sp Osp[r0] + w1*sum_sp Osp[r1]
__global__ __launch_bounds__(256) void k_final(
    const float* __restrict__ Obase, const int* __restrict__ counts,
    const int* __restrict__ tok_e, const int* __restrict__ tok_p,
    const float* __restrict__ tok_w, float* __restrict__ out) {
    __shared__ int sb[NE];
    int t = blockIdx.x;
    if (threadIdx.x == 0) {
        int s = 0;
        for (int e = 0; e < NE; e++) { sb[e] = s; s += counts[e]; }
    }
    __syncthreads();
    int r0 = sb[tok_e[t * 2 + 0]] + tok_p[t * 2 + 0];
    int r1 = sb[tok_e[t * 2 + 1]] + tok_p[t * 2 + 1];
    float w0 = tok_w[t * 2 + 0], w1 = tok_w[t * 2 + 1];
    int i = threadIdx.x * 4;
    float4 s0 = {0, 0, 0, 0}, s1 = {0, 0, 0, 0};
#pragma unroll
    for (int sp = 0; sp < 4; sp++) {
        const float* O = Obase + (size_t)sp * 4194304;
        float4 a = *(const float4*)(O + (size_t)r0 * D_EMB + i);
        float4 b = *(const float4*)(O + (size_t)r1 * D_EMB + i);
        s0.x += a.x; s0.y += a.y; s0.z += a.z; s0.w += a.w;
        s1.x += b.x; s1.y += b.y; s1.z += b.z; s1.w += b.w;
    }
    float4 o;
    o.x = w0 * s0.x + w1 * s1.x;
    o.y = w0 * s0.y + w1 * s1.y;
    o.z = w0 * s0.z + w1 * s1.z;
    o.w = w0 * s0.w + w1 * s1.w;
    *(float4*)(out + (size_t)t * D_EMB + i) = o;
}

extern "C" void kernel_launch(void* const* d_in, const int* in_sizes, int n_in,
                              void* d_out, int out_size, void* d_ws, size_t ws_size,
                              hipStream_t stream) {
    const float* x    = (const float*)d_in[0];
    const float* mask = (const float*)d_in[1];
    const float* Wr   = (const float*)d_in[2];
    const float* W1   = (const float*)d_in[3];   // [8,1024,4096]
    const float* W2   = (const float*)d_in[4];   // [8,4096,1024]
    float* out = (float*)d_out;

    char* ws = (char*)d_ws;
    const size_t MB = 1024 * 1024;
    int*      counts = (int*)(ws + 0);
    int*      elist  = (int*)(ws + 1024);
    int*      tok_e  = (int*)(ws + 1024 + 65536);
    int*      tok_p  = (int*)(ws + 1024 + 65536 + 16384);
    float*    tok_w  = (float*)(ws + 1024 + 65536 + 32768);
    _Float16* xh     = (_Float16*)(ws + 1 * MB);    // 4 MB
    _Float16* W1T    = (_Float16*)(ws + 8 * MB);    // 64 MB tiled [e][kt16][4096][64]
    _Float16* W2T    = (_Float16*)(ws + 72 * MB);   // 64 MB tiled [e][kt64][1024][64]
    _Float16* H      = (_Float16*)(ws + 136 * MB);  // 32 MB [4096][4096]
    float*    Obuf   = (float*)(ws + 168 * MB);     // 64 MB [4 sp][4096][1024]

    k_zero<<<1, 64, 0, stream>>>(counts);
    k_router<<<T_TOK / 4, 256, 0, stream>>>(x, mask, Wr, xh, counts, elist, tok_e, tok_p, tok_w);
    k_transpose<<<dim3(512, 1, 16), 256, 0, stream>>>(W1, W2, W1T, W2T);
    k_gemm1<<<dim3(32, 16, NE), 256, 0, stream>>>(xh, W1T, counts, elist, H);
    k_gemm2<<<dim3(8, 16, 32), 256, 0, stream>>>(H, W2T, counts, Obuf);
    k_final<<<T_TOK, 256, 0, stream>>>(Obuf, counts, tok_e, tok_p, tok_w, out);
}